// Round 1
// baseline (222.018 us; speedup 1.0000x reference)
//
#include <hip/hip_runtime.h>
#include <hip/hip_bf16.h>
#include <stdint.h>

// MoE grouped linear: y[t] = relu(x[t] @ W[idxs[t]] + b[idxs[t]])
// T=16384, D_IN=D_OUT=1024, E=8.
// R7: pipeline 4 kernels -> 2.
//  k_front (513 blocks x 1024): block 0 = count+scan+table+SCATTER fused
//    (scan already yields each thread's exclusive base -> ballot kernel was
//    redundant); blocks 1..512 = W transpose (128x128 tiles), runs
//    concurrently with prep. Per-block dtype detect (no flag dependency).
//  k_gemm: A gathered DIRECTLY from x via per-lane global_load_lds addresses
//    (Aperm pass eliminated). A kept fp32 in LDS (16B-granule XOR swizzle
//    over row&15 -- same conflict-free pattern as proven bf16 swizzle),
//    converted to bf16 at fragment load. BN 64->128: 32 MFMA/wave per
//    barrier pair (was 16), A re-reads halved.

#define T_TOK 16384
#define DIN   1024
#define DOUT  1024
#define NE    8
#define BM    128
#define BN    128
#define BK    64
#define TPX   17                  // A-tiles per XCD slot (8*17 = 136)
#define MAX_TILES 136
#define MP_MAX (T_TOK + NE * BM)  // 17408 padded rows max

typedef __attribute__((ext_vector_type(8))) short short8;
typedef __attribute__((ext_vector_type(4))) short short4v;
typedef __attribute__((ext_vector_type(4))) float floatx4;
typedef __attribute__((ext_vector_type(4))) int int4v;

__device__ __forceinline__ short f2b(float f) {
  return __builtin_bit_cast(short, __float2bfloat16(f));
}
__device__ __forceinline__ float b2f(unsigned short u) {
  unsigned v = ((unsigned)u) << 16;
  return __builtin_bit_cast(float, v);
}
__device__ __forceinline__ void glds16(const void* g, void* l) {
  __builtin_amdgcn_global_load_lds(
      (__attribute__((address_space(1))) void*)g,
      (__attribute__((address_space(3))) void*)l, 16, 0, 0);
}

// ws layout (bytes)
#define FLAG_OFF    0
#define NTILES_OFF  64
#define TABLE_OFF   1024   // MAX_TILES * int4 (2176 B)
#define TPAD_OFF    8192   // MP_MAX ints (69632 B)
#define WT_OFF      81920  // 16 MB bf16 [E][n][k]
#define WS_NEED     (81920UL + (size_t)NE * DIN * DOUT * 2)

// ---- k_front: block 0 = prep+scatter; blocks 1..512 = W transpose.
__global__ __launch_bounds__(1024) void k_front(
    const unsigned short* __restrict__ xu, const int* __restrict__ idxs,
    const void* __restrict__ Wsrc, short* __restrict__ Wt,
    int* __restrict__ flag, int* __restrict__ ntiles,
    int4v* __restrict__ table, int* __restrict__ tpad) {
  __shared__ int fS;
  __shared__ unsigned short tile[128][130];            // transpose path
  __shared__ int wtot[16][NE], waveBase[16][NE];       // prep path
  __shared__ int totS[NE], padS[NE + 1];

  int tid = threadIdx.x;
  // per-block dtype detect: fp32 iff any of first 256 ushorts has "exponent"
  // byte >= 0xC0 (fp32 low-half mantissa bits are ~uniform; bf16 N(0,1)
  // exponents are ~126 < 0xC0). Zero cross-block dependency.
  if (tid == 0) fS = 0;
  __syncthreads();
  if (tid < 256) {
    int ex = (xu[tid] >> 7) & 0xFF;
    if (ex >= 0xC0) atomicOr(&fS, 1);
  }
  __syncthreads();
  int fp32 = fS;

  if (blockIdx.x != 0) {
    // ---- transpose W [E][k][n] -> Wt [E][n][k] bf16, 128x128 region ----
    int b = blockIdx.x - 1;          // [0,512)
    int e = b >> 6, kt = (b >> 3) & 7, nt8 = b & 7;
    size_t ibase = (size_t)e * DIN * DOUT + (size_t)(kt * 128) * DOUT + nt8 * 128;
    int k = tid >> 3, n16 = (tid & 7) * 16;
    if (fp32) {
      const float* p = (const float*)Wsrc + ibase + (size_t)k * DOUT + n16;
      #pragma unroll
      for (int g = 0; g < 4; ++g) {
        floatx4 a = *(const floatx4*)(p + g * 4);
        #pragma unroll
        for (int j = 0; j < 4; ++j) tile[k][n16 + g * 4 + j] = (unsigned short)f2b(a[j]);
      }
    } else {
      const short* p = (const short*)Wsrc + ibase + (size_t)k * DOUT + n16;
      #pragma unroll
      for (int g = 0; g < 2; ++g) {
        short8 v = *(const short8*)(p + g * 8);
        #pragma unroll
        for (int j = 0; j < 8; ++j) tile[k][n16 + g * 8 + j] = (unsigned short)v[j];
      }
    }
    __syncthreads();
    int n = tid >> 3, k16 = (tid & 7) * 16;
    short8 o0, o1;
    #pragma unroll
    for (int j = 0; j < 8; ++j) {
      o0[j] = (short)tile[k16 + j][n];
      o1[j] = (short)tile[k16 + 8 + j][n];
    }
    size_t obase = (size_t)e * DOUT * DIN + (size_t)(nt8 * 128 + n) * DIN + kt * 128 + k16;
    *(short8*)(Wt + obase) = o0;
    *(short8*)(Wt + obase + 8) = o1;
    return;
  }

  // ---- block 0: count -> scan -> table -> scatter -> pad fill ----
  int lane = tid & 63, w = tid >> 6;
  if (tid == 0) *flag = fp32;

  int c[NE];
  #pragma unroll
  for (int e = 0; e < NE; ++e) c[e] = 0;
  const int4v* iv = (const int4v*)idxs;
  int4v vv[4];
  #pragma unroll
  for (int it = 0; it < 4; ++it) {
    vv[it] = iv[tid * 4 + it];
    ++c[vv[it].x]; ++c[vv[it].y]; ++c[vv[it].z]; ++c[vv[it].w];
  }
  // wave-level inclusive scan per expert
  int incl[NE];
  #pragma unroll
  for (int e = 0; e < NE; ++e) {
    incl[e] = c[e];
    #pragma unroll
    for (int d = 1; d < 64; d <<= 1) {
      int o = __shfl_up(incl[e], d);
      if (lane >= d) incl[e] += o;
    }
  }
  if (lane == 63) {
    #pragma unroll
    for (int e = 0; e < NE; ++e) wtot[w][e] = incl[e];
  }
  __syncthreads();
  if (tid < NE) {
    int s = 0;
    for (int ww = 0; ww < 16; ++ww) s += wtot[ww][tid];
    totS[tid] = s;
  }
  __syncthreads();
  if (tid == 0) {
    int p = 0, tc = 0;
    for (int e = 0; e < NE; ++e) {
      padS[e] = p;
      int cn = totS[e];
      int nmt = (cn + BM - 1) >> 7;
      for (int m = 0; m < nmt; ++m) table[tc++] = (int4v){e, p + m * BM, 0, 0};
      p += nmt * BM;
    }
    padS[NE] = p;
    *ntiles = tc;
  }
  __syncthreads();
  if (tid < 128) {
    int ww = tid >> 3, e = tid & 7;
    int s = padS[e];
    for (int wp = 0; wp < ww; ++wp) s += wtot[wp][e];
    waveBase[ww][e] = s;
  }
  __syncthreads();
  // each thread places its 16 tokens at its exclusive-scan base (in order)
  int base[NE];
  #pragma unroll
  for (int e = 0; e < NE; ++e) base[e] = waveBase[w][e] + incl[e] - c[e];
  #pragma unroll
  for (int it = 0; it < 4; ++it) {
    #pragma unroll
    for (int cm = 0; cm < 4; ++cm) {
      int te = vv[it][cm];
      int tk = tid * 16 + it * 4 + cm;
      #pragma unroll
      for (int e0 = 0; e0 < NE; ++e0)
        if (te == e0) tpad[base[e0]++] = tk;   // unrolled const idx: registers
    }
  }
  #pragma unroll
  for (int e = 0; e < NE; ++e) {
    int start = padS[e] + totS[e];
    int len = padS[e + 1] - start;
    if (tid < len) tpad[start + tid] = -1;
  }
}

// ---- GEMM: 128x128 tile, BK=64, A gathered from x (fp32 kept in LDS,
// cvt at frag load), B from Wt bf16. 2-barrier loop, glds16 staging.
__launch_bounds__(256, 3)
__global__ void k_gemm(const void* __restrict__ xv, const void* __restrict__ bv,
                       const short* __restrict__ Wt, const int* __restrict__ tpad,
                       const int* __restrict__ ntilesp, const int4v* __restrict__ table,
                       const int* __restrict__ flagp, void* __restrict__ outv) {
  int bid = blockIdx.x;
  int xcd = bid & 7;
  int s = bid >> 3;
  int nt = s & 7;                  // 8 n-tiles of 128
  int ti = s >> 3;                 // [0, TPX)
  int t = xcd * TPX + ti;
  if (t >= *ntilesp) return;
  int4v te = table[t];
  int e = te.x, arow0 = te.y;
  int fp32 = *flagp;

  int tid = threadIdx.x;
  int lane = tid & 63;
  int wave = tid >> 6;

  __shared__ char lA[BM * BK * 4];   // fp32: 128 rows x 256B; bf16 uses 16KB
  __shared__ short lB[BN * BK];      // 16 KB
  __shared__ int tokS[BM];

  if (tid < BM) tokS[tid] = tpad[arow0 + tid];
  __syncthreads();

  const short* WtE = Wt + (size_t)e * DOUT * DIN + (size_t)(nt * BN) * DIN;

  // B staging: 1024 16B-units; phys chunk p of row r holds logical p^(r&7).
  const short* bG[4];
  char* bL[4];
  #pragma unroll
  for (int s4 = 0; s4 < 4; ++s4) {
    int fl = tid + s4 * 256;
    int r = fl >> 3, p = fl & 7;
    int kc = p ^ (r & 7);
    bG[s4] = WtE + (size_t)r * DIN + kc * 8;
    bL[s4] = (char*)lB + (s4 * 256 + wave * 64) * 16;
  }

  int wm = wave & 1, wn = wave >> 1;   // 2x2 wave grid, each 64m x 64n
  int lrow = lane & 15, q = lane >> 4;
  int bOff[4][2];
  #pragma unroll
  for (int j = 0; j < 4; ++j) {
    int n = wn * 64 + j * 16 + lrow;
    #pragma unroll
    for (int h = 0; h < 2; ++h)
      bOff[j][h] = n * BK + (((h * 4 + q) ^ (n & 7)) * 8);
  }

  floatx4 acc[4][4];
  #pragma unroll
  for (int i = 0; i < 4; ++i)
    #pragma unroll
    for (int j = 0; j < 4; ++j)
      acc[i][j] = (floatx4){0.f, 0.f, 0.f, 0.f};

  if (fp32) {
    // A fp32: rows of 256B = 16 chunks(16B); phys p holds logical p^(r&15).
    const char* aG[8];
    char* aL[8];
    #pragma unroll
    for (int s4 = 0; s4 < 8; ++s4) {
      int fl = tid + s4 * 256;
      int r = fl >> 4, p = fl & 15;
      int lc = p ^ (r & 15);
      int tok = tokS[r];
      if (tok < 0) tok = 0;               // pad rows: harmless garbage, masked at store
      aG[s4] = (const char*)xv + (size_t)tok * (DIN * 4) + lc * 16;
      aL[s4] = lA + (s4 * 256 + wave * 64) * 16;
    }
    int aOff[4][2];   // addr of logical unit 2c; unit 2c+1 = addr ^ 16
    #pragma unroll
    for (int i = 0; i < 4; ++i) {
      int m = wm * 64 + i * 16 + lrow;
      #pragma unroll
      for (int h = 0; h < 2; ++h)
        aOff[i][h] = m * 256 + ((((h * 4 + q) * 2) ^ (m & 15)) * 16);
    }
    for (int k0 = 0; k0 < DIN; k0 += BK) {
      __syncthreads();
      #pragma unroll
      for (int s4 = 0; s4 < 4; ++s4) glds16(bG[s4] + k0, bL[s4]);
      #pragma unroll
      for (int s4 = 0; s4 < 8; ++s4) glds16(aG[s4] + k0 * 4, aL[s4]);
      __syncthreads();
      #pragma unroll
      for (int h = 0; h < 2; ++h) {
        short8 af[4], bf[4];
        #pragma unroll
        for (int i = 0; i < 4; ++i) {
          int a0 = aOff[i][h];
          floatx4 f0 = *(const floatx4*)(lA + a0);
          floatx4 f1 = *(const floatx4*)(lA + (a0 ^ 16));
          short8 v;
          v[0] = f2b(f0[0]); v[1] = f2b(f0[1]); v[2] = f2b(f0[2]); v[3] = f2b(f0[3]);
          v[4] = f2b(f1[0]); v[5] = f2b(f1[1]); v[6] = f2b(f1[2]); v[7] = f2b(f1[3]);
          af[i] = v;
        }
        #pragma unroll
        for (int j = 0; j < 4; ++j) bf[j] = *(const short8*)(lB + bOff[j][h]);
        // SWAPPED: D[p][c] = sum_k Wt[n-frag p][k] * A[m-frag c][k]
        #pragma unroll
        for (int i = 0; i < 4; ++i)
          #pragma unroll
          for (int j = 0; j < 4; ++j)
            acc[i][j] = __builtin_amdgcn_mfma_f32_16x16x32_bf16(bf[j], af[i], acc[i][j], 0, 0, 0);
      }
    }
  } else {
    // A bf16: rows of 128B = 8 chunks(16B); phys p holds logical p^(r&7).
    const char* aG[4];
    char* aL[4];
    #pragma unroll
    for (int s4 = 0; s4 < 4; ++s4) {
      int fl = tid + s4 * 256;
      int r = fl >> 3, p = fl & 7;
      int kc = p ^ (r & 7);
      int tok = tokS[r];
      if (tok < 0) tok = 0;
      aG[s4] = (const char*)xv + (size_t)tok * (DIN * 2) + kc * 16;
      aL[s4] = lA + (s4 * 256 + wave * 64) * 16;
    }
    int aOff[4][2];  // in shorts
    #pragma unroll
    for (int i = 0; i < 4; ++i) {
      int m = wm * 64 + i * 16 + lrow;
      #pragma unroll
      for (int h = 0; h < 2; ++h)
        aOff[i][h] = m * BK + (((h * 4 + q) ^ (m & 7)) * 8);
    }
    for (int k0 = 0; k0 < DIN; k0 += BK) {
      __syncthreads();
      #pragma unroll
      for (int s4 = 0; s4 < 4; ++s4) glds16(bG[s4] + k0, bL[s4]);
      #pragma unroll
      for (int s4 = 0; s4 < 4; ++s4) glds16(aG[s4] + k0 * 2, aL[s4]);
      __syncthreads();
      #pragma unroll
      for (int h = 0; h < 2; ++h) {
        short8 af[4], bf[4];
        #pragma unroll
        for (int i = 0; i < 4; ++i) af[i] = *(const short8*)((const short*)lA + aOff[i][h]);
        #pragma unroll
        for (int j = 0; j < 4; ++j) bf[j] = *(const short8*)(lB + bOff[j][h]);
        #pragma unroll
        for (int i = 0; i < 4; ++i)
          #pragma unroll
          for (int j = 0; j < 4; ++j)
            acc[i][j] = __builtin_amdgcn_mfma_f32_16x16x32_bf16(bf[j], af[i], acc[i][j], 0, 0, 0);
      }
    }
  }

  // epilogue: n = nt*128 + wn*64 + j*16 + q*4 + r ; m = wm*64 + i*16 + lrow
  #pragma unroll
  for (int i = 0; i < 4; ++i) {
    int tok = tokS[wm * 64 + i * 16 + lrow];
    if (tok < 0) continue;
    size_t rowb = (size_t)tok * DOUT + nt * BN + wn * 64 + q * 4;
    #pragma unroll
    for (int j = 0; j < 4; ++j) {
      int n = nt * BN + wn * 64 + j * 16 + q * 4;
      if (fp32) {
        floatx4 b4 = *(const floatx4*)((const float*)bv + e * DOUT + n);
        floatx4 o;
        #pragma unroll
        for (int r = 0; r < 4; ++r) {
          float v = acc[i][j][r] + b4[r];
          o[r] = v > 0.f ? v : 0.f;
        }
        *(floatx4*)((float*)outv + rowb + j * 16) = o;
      } else {
        short4v b4 = *(const short4v*)((const short*)bv + e * DOUT + n);
        short4v o;
        #pragma unroll
        for (int r = 0; r < 4; ++r) {
          float v = acc[i][j][r] + b2f((unsigned short)b4[r]);
          o[r] = f2b(v > 0.f ? v : 0.f);
        }
        *(short4v*)((short*)outv + rowb + j * 16) = o;
      }
    }
  }
}

// ---- correct-but-slow fallback if ws too small
__global__ void k_fallback(const void* __restrict__ xv, const int* __restrict__ idxs,
                           const void* __restrict__ Wv, const void* __restrict__ bv,
                           void* __restrict__ outv) {
  __shared__ float xrow[DIN];
  __shared__ int sflag;
  int t = blockIdx.x;
  int e = idxs[t];
  if (threadIdx.x == 0) {
    const unsigned short* u = (const unsigned short*)xv;
    int f = 0;
    for (int i = 0; i < 256; ++i) { int ex = (u[i] >> 7) & 0xFF; if (ex >= 0xC0) f = 1; }
    sflag = f;
  }
  __syncthreads();
  int fp32 = sflag;
  for (int i = threadIdx.x; i < DIN; i += 256)
    xrow[i] = fp32 ? ((const float*)xv)[(size_t)t * DIN + i]
                   : b2f(((const unsigned short*)xv)[(size_t)t * DIN + i]);
  __syncthreads();
  float a[4] = {0.f, 0.f, 0.f, 0.f};
  for (int k = 0; k < DIN; ++k) {
    float xk = xrow[k];
    size_t wb = (size_t)e * DIN * DOUT + (size_t)k * DOUT + threadIdx.x;
    #pragma unroll
    for (int j = 0; j < 4; ++j) {
      float w = fp32 ? ((const float*)Wv)[wb + j * 256]
                     : b2f(((const unsigned short*)Wv)[wb + j * 256]);
      a[j] += xk * w;
    }
  }
  #pragma unroll
  for (int j = 0; j < 4; ++j) {
    int n = threadIdx.x + j * 256;
    float bias = fp32 ? ((const float*)bv)[e * DOUT + n]
                      : b2f(((const unsigned short*)bv)[e * DOUT + n]);
    float v = a[j] + bias;
    v = v > 0.f ? v : 0.f;
    size_t o = (size_t)t * DOUT + n;
    if (fp32) ((float*)outv)[o] = v;
    else      ((short*)outv)[o] = f2b(v);
  }
}

extern "C" void kernel_launch(void* const* d_in, const int* in_sizes, int n_in,
                              void* d_out, int out_size, void* d_ws, size_t ws_size,
                              hipStream_t stream) {
  const void* x    = d_in[0];
  const int*  idxs = (const int*)d_in[1];
  const void* W    = d_in[2];
  const void* bias = d_in[3];

  if (ws_size < WS_NEED) {
    k_fallback<<<T_TOK, 256, 0, stream>>>(x, idxs, W, bias, d_out);
    return;
  }
  char* ws = (char*)d_ws;
  int* flag    = (int*)(ws + FLAG_OFF);
  int* ntiles  = (int*)(ws + NTILES_OFF);
  int4v* table = (int4v*)(ws + TABLE_OFF);
  int* tpad    = (int*)(ws + TPAD_OFF);
  short* Wt    = (short*)(ws + WT_OFF);

  k_front<<<1 + NE * 64, 1024, 0, stream>>>((const unsigned short*)x, idxs, W, Wt,
                                            flag, ntiles, table, tpad);
  k_gemm<<<8 * 8 * TPX, 256, 0, stream>>>(x, bias, Wt, tpad, ntiles, table, flag, d_out);
}

// Round 2
// 202.024 us; speedup vs baseline: 1.0990x; 1.0990x over previous
//
#include <hip/hip_runtime.h>
#include <hip/hip_bf16.h>
#include <stdint.h>

// MoE grouped linear: y[t] = relu(x[t] @ W[idxs[t]] + b[idxs[t]])
// T=16384, D_IN=D_OUT=1024, E=8.
// R8: post-mortem of R7 -- fp32-A-in-LDS doubled LDS (48KB, occ 23%) and
// doubled per-K-step A ds_reads + 64 cvt/thread: LDS/VALU-bound, gemm 103us.
// Fix: k_front gains 1024 blocks converting x -> xb (bf16, 32MB ws) when
// input is fp32 (bf16 input: gemm reads x directly, same stride). GEMM is
// single-path bf16, BN=128, 33KB LDS, proven zero-conflict XOR swizzle,
// per-lane gather of token rows via global_load_lds (no Aperm pass).

#define T_TOK 16384
#define DIN   1024
#define DOUT  1024
#define NE    8
#define BM    128
#define BN    128
#define BK    64
#define TPX   17                  // A-tiles per XCD slot (8*17 = 136)
#define MAX_TILES 136
#define MP_MAX (T_TOK + NE * BM)  // 17408 padded rows max

typedef __attribute__((ext_vector_type(8))) short short8;
typedef __attribute__((ext_vector_type(4))) short short4v;
typedef __attribute__((ext_vector_type(4))) float floatx4;
typedef __attribute__((ext_vector_type(4))) int int4v;

__device__ __forceinline__ short f2b(float f) {
  return __builtin_bit_cast(short, __float2bfloat16(f));
}
__device__ __forceinline__ float b2f(unsigned short u) {
  unsigned v = ((unsigned)u) << 16;
  return __builtin_bit_cast(float, v);
}
__device__ __forceinline__ void glds16(const void* g, void* l) {
  __builtin_amdgcn_global_load_lds(
      (__attribute__((address_space(1))) void*)g,
      (__attribute__((address_space(3))) void*)l, 16, 0, 0);
}

// ws layout (bytes)
#define FLAG_OFF    0
#define NTILES_OFF  64
#define TABLE_OFF   1024   // MAX_TILES * int4 (2176 B)
#define TPAD_OFF    8192   // MP_MAX ints (69632 B)
#define WT_OFF      81920  // 16 MB bf16 [E][n][k]
#define XB_OFF      16859136  // 32 MB bf16 [T][k] (fp32 input only)
#define WS_NEED     (16859136UL + (size_t)T_TOK * DIN * 2)

#define TRANS_BLOCKS 512
#define CONV_BLOCKS  1024   // 1024 blk x 1024 thr x 16 elems = 16.78M

// ---- k_front: block 0 = prep+scatter; blocks [1,513) = W transpose;
//      blocks [513, 513+1024) = x fp32 -> bf16 convert (skipped if bf16 in).
__global__ __launch_bounds__(1024) void k_front(
    const unsigned short* __restrict__ xu, const int* __restrict__ idxs,
    const void* __restrict__ Wsrc, short* __restrict__ Wt, short* __restrict__ xb,
    int* __restrict__ flag, int* __restrict__ ntiles,
    int4v* __restrict__ table, int* __restrict__ tpad) {
  __shared__ int fS;
  __shared__ unsigned short tile[128][130];            // transpose path
  __shared__ int wtot[16][NE], waveBase[16][NE];       // prep path
  __shared__ int totS[NE], padS[NE + 1];

  int tid = threadIdx.x;
  // per-block dtype detect: fp32 iff any of first 256 ushorts has "exponent"
  // byte >= 0xC0 (fp32 low-half mantissa bits ~uniform; bf16 N(0,1)
  // exponents ~126 < 0xC0). Zero cross-block dependency.
  if (tid == 0) fS = 0;
  __syncthreads();
  if (tid < 256) {
    int ex = (xu[tid] >> 7) & 0xFF;
    if (ex >= 0xC0) atomicOr(&fS, 1);
  }
  __syncthreads();
  int fp32 = fS;

  if (blockIdx.x >= 1 + TRANS_BLOCKS) {
    // ---- x convert: fp32 -> bf16 into xb ----
    if (!fp32) return;
    int b2 = blockIdx.x - (1 + TRANS_BLOCKS);
    size_t base = ((size_t)b2 * 1024 + tid) * 16;
    const float* src = (const float*)xu + base;
    floatx4 a0 = *(const floatx4*)(src + 0);
    floatx4 a1 = *(const floatx4*)(src + 4);
    floatx4 a2 = *(const floatx4*)(src + 8);
    floatx4 a3 = *(const floatx4*)(src + 12);
    short8 o0, o1;
    #pragma unroll
    for (int j = 0; j < 4; ++j) {
      o0[j] = f2b(a0[j]); o0[4 + j] = f2b(a1[j]);
      o1[j] = f2b(a2[j]); o1[4 + j] = f2b(a3[j]);
    }
    *(short8*)(xb + base) = o0;
    *(short8*)(xb + base + 8) = o1;
    return;
  }

  if (blockIdx.x != 0) {
    // ---- transpose W [E][k][n] -> Wt [E][n][k] bf16, 128x128 region ----
    int b = blockIdx.x - 1;          // [0,512)
    int e = b >> 6, kt = (b >> 3) & 7, nt8 = b & 7;
    size_t ibase = (size_t)e * DIN * DOUT + (size_t)(kt * 128) * DOUT + nt8 * 128;
    int k = tid >> 3, n16 = (tid & 7) * 16;
    if (fp32) {
      const float* p = (const float*)Wsrc + ibase + (size_t)k * DOUT + n16;
      #pragma unroll
      for (int g = 0; g < 4; ++g) {
        floatx4 a = *(const floatx4*)(p + g * 4);
        #pragma unroll
        for (int j = 0; j < 4; ++j) tile[k][n16 + g * 4 + j] = (unsigned short)f2b(a[j]);
      }
    } else {
      const short* p = (const short*)Wsrc + ibase + (size_t)k * DOUT + n16;
      #pragma unroll
      for (int g = 0; g < 2; ++g) {
        short8 v = *(const short8*)(p + g * 8);
        #pragma unroll
        for (int j = 0; j < 8; ++j) tile[k][n16 + g * 8 + j] = (unsigned short)v[j];
      }
    }
    __syncthreads();
    int n = tid >> 3, k16 = (tid & 7) * 16;
    short8 o0, o1;
    #pragma unroll
    for (int j = 0; j < 8; ++j) {
      o0[j] = (short)tile[k16 + j][n];
      o1[j] = (short)tile[k16 + 8 + j][n];
    }
    size_t obase = (size_t)e * DOUT * DIN + (size_t)(nt8 * 128 + n) * DIN + kt * 128 + k16;
    *(short8*)(Wt + obase) = o0;
    *(short8*)(Wt + obase + 8) = o1;
    return;
  }

  // ---- block 0: count -> scan -> table -> scatter -> pad fill ----
  int lane = tid & 63, w = tid >> 6;
  if (tid == 0) *flag = fp32;

  int c[NE];
  #pragma unroll
  for (int e = 0; e < NE; ++e) c[e] = 0;
  const int4v* iv = (const int4v*)idxs;
  int4v vv[4];
  #pragma unroll
  for (int it = 0; it < 4; ++it) {
    vv[it] = iv[tid * 4 + it];
    ++c[vv[it].x]; ++c[vv[it].y]; ++c[vv[it].z]; ++c[vv[it].w];
  }
  // wave-level inclusive scan per expert
  int incl[NE];
  #pragma unroll
  for (int e = 0; e < NE; ++e) {
    incl[e] = c[e];
    #pragma unroll
    for (int d = 1; d < 64; d <<= 1) {
      int o = __shfl_up(incl[e], d);
      if (lane >= d) incl[e] += o;
    }
  }
  if (lane == 63) {
    #pragma unroll
    for (int e = 0; e < NE; ++e) wtot[w][e] = incl[e];
  }
  __syncthreads();
  if (tid < NE) {
    int s = 0;
    for (int ww = 0; ww < 16; ++ww) s += wtot[ww][tid];
    totS[tid] = s;
  }
  __syncthreads();
  if (tid == 0) {
    int p = 0, tc = 0;
    for (int e = 0; e < NE; ++e) {
      padS[e] = p;
      int cn = totS[e];
      int nmt = (cn + BM - 1) >> 7;
      for (int m = 0; m < nmt; ++m) table[tc++] = (int4v){e, p + m * BM, 0, 0};
      p += nmt * BM;
    }
    padS[NE] = p;
    *ntiles = tc;
  }
  __syncthreads();
  if (tid < 128) {
    int ww = tid >> 3, e = tid & 7;
    int s = padS[e];
    for (int wp = 0; wp < ww; ++wp) s += wtot[wp][e];
    waveBase[ww][e] = s;
  }
  __syncthreads();
  // each thread places its 16 tokens at its exclusive-scan base (in order)
  int base[NE];
  #pragma unroll
  for (int e = 0; e < NE; ++e) base[e] = waveBase[w][e] + incl[e] - c[e];
  #pragma unroll
  for (int it = 0; it < 4; ++it) {
    #pragma unroll
    for (int cm = 0; cm < 4; ++cm) {
      int te = vv[it][cm];
      int tk = tid * 16 + it * 4 + cm;
      #pragma unroll
      for (int e0 = 0; e0 < NE; ++e0)
        if (te == e0) tpad[base[e0]++] = tk;   // unrolled const idx: registers
    }
  }
  #pragma unroll
  for (int e = 0; e < NE; ++e) {
    int start = padS[e] + totS[e];
    int len = padS[e + 1] - start;
    if (tid < len) tpad[start + tid] = -1;
  }
}

// ---- GEMM: 128x128 tile, BK=64 (16 iters), single-path bf16.
// A gathered per-row from bf16 source (xb if fp32 input, else x itself)
// via per-lane glds addresses; XOR-swizzled LDS (16B granule, chunk^(row&7))
// -- measured zero bank conflicts. Operand-swapped MFMA epilogue.
__launch_bounds__(256, 4)
__global__ void k_gemm(const void* __restrict__ xv, const short* __restrict__ xb,
                       const void* __restrict__ bv,
                       const short* __restrict__ Wt, const int* __restrict__ tpad,
                       const int* __restrict__ ntilesp, const int4v* __restrict__ table,
                       const int* __restrict__ flagp, void* __restrict__ outv) {
  int bid = blockIdx.x;
  int xcd = bid & 7;
  int s = bid >> 3;
  int nt = s & 7;                  // 8 n-tiles of 128
  int ti = s >> 3;                 // [0, TPX)
  int t = xcd * TPX + ti;
  if (t >= *ntilesp) return;
  int4v te = table[t];
  int e = te.x, arow0 = te.y;
  int fp32 = *flagp;

  int tid = threadIdx.x;
  int lane = tid & 63;
  int wave = tid >> 6;

  __shared__ short lA[BM * BK];   // 16 KB, rows of 128B (8 chunks), swizzled
  __shared__ short lB[BN * BK];   // 16 KB
  __shared__ int tokS[BM];

  if (tid < BM) tokS[tid] = tpad[arow0 + tid];
  __syncthreads();

  const short* WtE = Wt + (size_t)e * DOUT * DIN + (size_t)(nt * BN) * DIN;
  const char* aBase = fp32 ? (const char*)xb : (const char*)xv;  // bf16 rows, 2048 B

  // staging: 1024 16B-units each for A and B; 4/thread.
  // phys chunk p of row r holds logical chunk p^(r&7).
  const char* aG[4];
  const short* bG[4];
  char *aL[4], *bL[4];
  #pragma unroll
  for (int s4 = 0; s4 < 4; ++s4) {
    int fl = tid + s4 * 256;
    int r = fl >> 3, p = fl & 7;
    int kc = p ^ (r & 7);
    int tok = tokS[r];
    if (tok < 0) tok = 0;   // pad rows: harmless data, masked at store
    aG[s4] = aBase + (size_t)tok * (DIN * 2) + kc * 16;
    aL[s4] = (char*)lA + (s4 * 256 + wave * 64) * 16;
    bG[s4] = WtE + (size_t)r * DIN + kc * 8;
    bL[s4] = (char*)lB + (s4 * 256 + wave * 64) * 16;
  }

  int wm = wave & 1, wn = wave >> 1;   // 2x2 wave grid, each 64m x 64n
  int lrow = lane & 15, q = lane >> 4;
  // frag reads: logical chunk c = h*4+q of row m -> phys m*BK + (c^(m&7))*8 shorts
  int aOff[4][2], bOff[4][2];
  #pragma unroll
  for (int i = 0; i < 4; ++i) {
    int m = wm * 64 + i * 16 + lrow;
    #pragma unroll
    for (int h = 0; h < 2; ++h)
      aOff[i][h] = m * BK + (((h * 4 + q) ^ (m & 7)) * 8);
  }
  #pragma unroll
  for (int j = 0; j < 4; ++j) {
    int n = wn * 64 + j * 16 + lrow;
    #pragma unroll
    for (int h = 0; h < 2; ++h)
      bOff[j][h] = n * BK + (((h * 4 + q) ^ (n & 7)) * 8);
  }

  floatx4 acc[4][4];
  #pragma unroll
  for (int i = 0; i < 4; ++i)
    #pragma unroll
    for (int j = 0; j < 4; ++j)
      acc[i][j] = (floatx4){0.f, 0.f, 0.f, 0.f};

  for (int k0 = 0; k0 < DIN; k0 += BK) {
    __syncthreads();
    #pragma unroll
    for (int s4 = 0; s4 < 4; ++s4) glds16(bG[s4] + k0, bL[s4]);
    #pragma unroll
    for (int s4 = 0; s4 < 4; ++s4) glds16(aG[s4] + k0 * 2, aL[s4]);
    __syncthreads();
    #pragma unroll
    for (int h = 0; h < 2; ++h) {
      short8 af[4], bf[4];
      #pragma unroll
      for (int i = 0; i < 4; ++i) af[i] = *(const short8*)(lA + aOff[i][h]);
      #pragma unroll
      for (int j = 0; j < 4; ++j) bf[j] = *(const short8*)(lB + bOff[j][h]);
      // SWAPPED: D[p][c] = sum_k Wt[n-frag p][k] * A[m-frag c][k]
      #pragma unroll
      for (int i = 0; i < 4; ++i)
        #pragma unroll
        for (int j = 0; j < 4; ++j)
          acc[i][j] = __builtin_amdgcn_mfma_f32_16x16x32_bf16(bf[j], af[i], acc[i][j], 0, 0, 0);
    }
  }

  // epilogue: n = nt*128 + wn*64 + j*16 + q*4 + r (regs contiguous in n);
  //           m = wm*64 + i*16 + lrow
  #pragma unroll
  for (int i = 0; i < 4; ++i) {
    int tok = tokS[wm * 64 + i * 16 + lrow];
    if (tok < 0) continue;
    size_t rowb = (size_t)tok * DOUT + nt * BN + wn * 64 + q * 4;
    #pragma unroll
    for (int j = 0; j < 4; ++j) {
      int n = nt * BN + wn * 64 + j * 16 + q * 4;
      if (fp32) {
        floatx4 b4 = *(const floatx4*)((const float*)bv + e * DOUT + n);
        floatx4 o;
        #pragma unroll
        for (int r = 0; r < 4; ++r) {
          float v = acc[i][j][r] + b4[r];
          o[r] = v > 0.f ? v : 0.f;
        }
        *(floatx4*)((float*)outv + rowb + j * 16) = o;
      } else {
        short4v b4 = *(const short4v*)((const short*)bv + e * DOUT + n);
        short4v o;
        #pragma unroll
        for (int r = 0; r < 4; ++r) {
          float v = acc[i][j][r] + b2f((unsigned short)b4[r]);
          o[r] = f2b(v > 0.f ? v : 0.f);
        }
        *(short4v*)((short*)outv + rowb + j * 16) = o;
      }
    }
  }
}

// ---- correct-but-slow fallback if ws too small
__global__ void k_fallback(const void* __restrict__ xv, const int* __restrict__ idxs,
                           const void* __restrict__ Wv, const void* __restrict__ bv,
                           void* __restrict__ outv) {
  __shared__ float xrow[DIN];
  __shared__ int sflag;
  int t = blockIdx.x;
  int e = idxs[t];
  if (threadIdx.x == 0) {
    const unsigned short* u = (const unsigned short*)xv;
    int f = 0;
    for (int i = 0; i < 256; ++i) { int ex = (u[i] >> 7) & 0xFF; if (ex >= 0xC0) f = 1; }
    sflag = f;
  }
  __syncthreads();
  int fp32 = sflag;
  for (int i = threadIdx.x; i < DIN; i += 256)
    xrow[i] = fp32 ? ((const float*)xv)[(size_t)t * DIN + i]
                   : b2f(((const unsigned short*)xv)[(size_t)t * DIN + i]);
  __syncthreads();
  float a[4] = {0.f, 0.f, 0.f, 0.f};
  for (int k = 0; k < DIN; ++k) {
    float xk = xrow[k];
    size_t wb = (size_t)e * DIN * DOUT + (size_t)k * DOUT + threadIdx.x;
    #pragma unroll
    for (int j = 0; j < 4; ++j) {
      float w = fp32 ? ((const float*)Wv)[wb + j * 256]
                     : b2f(((const unsigned short*)Wv)[wb + j * 256]);
      a[j] += xk * w;
    }
  }
  #pragma unroll
  for (int j = 0; j < 4; ++j) {
    int n = threadIdx.x + j * 256;
    float bias = fp32 ? ((const float*)bv)[e * DOUT + n]
                      : b2f(((const unsigned short*)bv)[e * DOUT + n]);
    float v = a[j] + bias;
    v = v > 0.f ? v : 0.f;
    size_t o = (size_t)t * DOUT + n;
    if (fp32) ((float*)outv)[o] = v;
    else      ((short*)outv)[o] = f2b(v);
  }
}

extern "C" void kernel_launch(void* const* d_in, const int* in_sizes, int n_in,
                              void* d_out, int out_size, void* d_ws, size_t ws_size,
                              hipStream_t stream) {
  const void* x    = d_in[0];
  const int*  idxs = (const int*)d_in[1];
  const void* W    = d_in[2];
  const void* bias = d_in[3];

  if (ws_size < WS_NEED) {
    k_fallback<<<T_TOK, 256, 0, stream>>>(x, idxs, W, bias, d_out);
    return;
  }
  char* ws = (char*)d_ws;
  int* flag    = (int*)(ws + FLAG_OFF);
  int* ntiles  = (int*)(ws + NTILES_OFF);
  int4v* table = (int4v*)(ws + TABLE_OFF);
  int* tpad    = (int*)(ws + TPAD_OFF);
  short* Wt    = (short*)(ws + WT_OFF);
  short* xb    = (short*)(ws + XB_OFF);

  k_front<<<1 + TRANS_BLOCKS + CONV_BLOCKS, 1024, 0, stream>>>(
      (const unsigned short*)x, idxs, W, Wt, xb, flag, ntiles, table, tpad);
  k_gemm<<<8 * 8 * TPX, 256, 0, stream>>>(x, xb, bias, Wt, tpad, ntiles, table, flag, d_out);
}